// Round 11
// baseline (676.001 us; speedup 1.0000x reference)
//
#include <hip/hip_runtime.h>

#define B_TOTAL 131072
#define PD 200
#define KAPPA 0.8f
#define LAMDA 0.9999f
#define YITA 0.5f
#define MS_KS 216   // M LDS k-stride (27 16B slots, odd -> minimal-conflict A reads)
#define HB_RS 72    // hebb LDS row-stride (9 slots, odd)

typedef short short8 __attribute__((ext_vector_type(8)));
typedef short short4v __attribute__((ext_vector_type(4)));
typedef float f32x16 __attribute__((ext_vector_type(16)));
typedef unsigned uint4v __attribute__((ext_vector_type(4)));

static __device__ __forceinline__ float bf2f(unsigned short h) {
  union { unsigned u; float f; } v; v.u = ((unsigned)h) << 16; return v.f;
}
static __device__ __forceinline__ unsigned short f2bf(float f) {
  union { float f; unsigned u; } v; v.f = f;
  unsigned r = v.u + 0x7FFFu + ((v.u >> 16) & 1u);
  return (unsigned short)(r >> 16);
}
static __device__ __forceinline__ float fp_nl(float v) {  // clip(leaky_relu(v),-1,1)
  float t = fmaxf(v, 0.01f * v);
  return fminf(1.f, fmaxf(-1.f, t));
}
static __device__ __forceinline__ unsigned pkbf(float lo, float hi) {
  unsigned r;
  asm("v_cvt_pk_bf16_f32 %0, %1, %2" : "=v"(r) : "v"(lo), "v"(hi));
  return r;
}
// verified R2-R10: swaps 32-lane halves between a,b
static __device__ __forceinline__ void swap32(unsigned &a, unsigned &b) {
  asm("s_nop 1\n\tv_permlane32_swap_b32 %0, %1" : "+v"(a), "+v"(b));
}
static __device__ __forceinline__ uint4v mk4(unsigned a, unsigned b, unsigned c, unsigned d) {
  uint4v v; v[0] = a; v[1] = b; v[2] = c; v[3] = d; return v;
}
static __device__ __forceinline__ short8 u4s8(uint4v w) {
  union { uint4v u; short8 s; } x; x.u = w; return x.s;
}

__global__ void tem_init_m(const float* __restrict__ Min, float* __restrict__ oM) {
  int i = blockIdx.x * 256 + threadIdx.x;
  if (i < PD * PD) oM[i] = LAMDA * Min[i];
}

// ---- tem_pre: high-occupancy kernel owning the o_g / o_x expansion (205 MB,
// 60% of output bytes). Recomputes g2/xc (cheap) so tem_main needs no extra
// workspace. 1024 blocks x 256 thr, 12.8 KB LDS -> 4 blocks/CU, BW-bound.
__global__ __launch_bounds__(256, 4) void tem_pre(
    const float* __restrict__ xin, const float* __restrict__ gin,
    const float* __restrict__ Wc,
    const float* __restrict__ W1gg, const float* __restrict__ b1gg,
    const float* __restrict__ W2gg, const float* __restrict__ b2gg,
    float* __restrict__ o_g, float* __restrict__ o_x) {
  __shared__ unsigned short xcS[128 * 10];
  __shared__ float g2S[128 * 20];
  const int tid = threadIdx.x;
  const int r0 = blockIdx.x * 128;

  if (tid < 128) {
    const int rq = r0 + tid;
    float gv[20];
#pragma unroll
    for (int i = 0; i < 20; ++i) gv[i] = gin[(size_t)rq * 20 + i];
    float out20[20];
#pragma unroll
    for (int o = 0; o < 20; ++o) out20[o] = b2gg[o];
#pragma unroll 1
    for (int u = 0; u < 40; ++u) {           // streaming MLP: code ~10x smaller
      float hu = b1gg[u];
#pragma unroll
      for (int i = 0; i < 20; ++i) hu += gv[i] * W1gg[i * 40 + u];
      hu = (hu > 0.f) ? hu : (expf(hu) - 1.f);
#pragma unroll
      for (int o = 0; o < 20; ++o) out20[o] += hu * W2gg[u * 20 + o];
    }
#pragma unroll
    for (int o = 0; o < 20; ++o) g2S[tid * 20 + o] = tanhf(out20[o]);
  } else {
    const int rr2 = tid - 128;
    const int rq = r0 + rr2;
    float xc[10];
#pragma unroll
    for (int o = 0; o < 10; ++o) xc[o] = 0.f;
#pragma unroll 1
    for (int j = 0; j < 45; ++j) {
      const float xv = xin[(size_t)rq * 45 + j];
#pragma unroll
      for (int o = 0; o < 10; ++o) xc[o] += xv * Wc[j * 10 + o];
    }
#pragma unroll
    for (int o = 0; o < 10; ++o) xcS[rr2 * 10 + o] = f2bf(xc[o]);
  }
  __syncthreads();
  for (int i = tid; i < 128 * 200; i += 256) {
    const int rP = i / 200, j = i - rP * 200;
    o_g[(size_t)(r0 + rP) * 200 + j] = g2S[rP * 20 + j / 10];
    o_x[(size_t)(r0 + rP) * 200 + j] = bf2f(xcS[rP * 10 + (j % 10)]);
  }
}

// ---- dual-retrieval macros (verified R10)
#define LDMS(nt, kc) (*(const short8*)(Ms + (((nt) * 32 + cl) * MS_KS + (kc) * 16 + hi * 8)))
#define PFLD(KC) (((const uint4v*)Pb)[(pbW + (KC)) * 64 + lane])
#define PFST(KC, V) (((uint4v*)Pb)[(pbW + (KC)) * 64 + lane] = (V))

#define MFMA_V(ACC, A, B) ACC = __builtin_amdgcn_mfma_f32_32x32x16_bf16(A, B, ACC, 0, 0, 0)
#define MFMA_AG(ACC, A, B) asm("v_mfma_f32_32x32x16_bf16 %0, %1, %2, %0" : "+a"(ACC) : "v"(A), "v"(B))

#define STEP2(PFA, KC) do { \
  const short8 _bA = u4s8(PFA); \
  const short8 _bB = u4s8(PFLD(KC)); \
  { const short8 _a = LDMS(0, KC); MFMA_V(accA0, _a, _bA); MFMA_AG(accB0, _a, _bB); } \
  { const short8 _a = LDMS(1, KC); MFMA_V(accA1, _a, _bA); MFMA_AG(accB1, _a, _bB); } \
  { const short8 _a = LDMS(2, KC); MFMA_V(accA2, _a, _bA); MFMA_AG(accB2, _a, _bB); } \
  { const short8 _a = LDMS(3, KC); MFMA_V(accA3, _a, _bA); MFMA_AG(accB3, _a, _bB); } \
  { const short8 _a = LDMS(4, KC); MFMA_V(accA4, _a, _bA); MFMA_AG(accB4, _a, _bB); } \
  { const short8 _a = LDMS(5, KC); MFMA_V(accA5, _a, _bA); MFMA_AG(accB5, _a, _bB); } \
  { const short8 _a = LDMS(6, KC); MFMA_V(accA6, _a, _bA); MFMA_AG(accB6, _a, _bB); } \
  __builtin_amdgcn_sched_barrier(0); \
} while (0)

#define REPACK_LO_R(ACC, PF) do { \
  unsigned P0 = pkbf(fp_nl(ACC[0]), fp_nl(ACC[1])); \
  unsigned P1 = pkbf(fp_nl(ACC[2]), fp_nl(ACC[3])); \
  unsigned P2 = pkbf(fp_nl(ACC[4]), fp_nl(ACC[5])); \
  unsigned P3 = pkbf(fp_nl(ACC[6]), fp_nl(ACC[7])); \
  swap32(P0, P2); swap32(P1, P3); \
  PF = mk4(P0, P1, P2, P3); \
} while (0)
#define REPACK_HI_R(ACC, PF) do { \
  unsigned P4 = pkbf(fp_nl(ACC[8]),  fp_nl(ACC[9])); \
  unsigned P5 = pkbf(fp_nl(ACC[10]), fp_nl(ACC[11])); \
  unsigned P6 = pkbf(fp_nl(ACC[12]), fp_nl(ACC[13])); \
  unsigned P7 = pkbf(fp_nl(ACC[14]), fp_nl(ACC[15])); \
  swap32(P4, P6); swap32(P5, P7); \
  PF = mk4(P4, P5, P6, P7); \
} while (0)
#define REPACK_LO_L(ACC, KC) do { \
  unsigned P0 = pkbf(fp_nl(ACC[0]), fp_nl(ACC[1])); \
  unsigned P1 = pkbf(fp_nl(ACC[2]), fp_nl(ACC[3])); \
  unsigned P2 = pkbf(fp_nl(ACC[4]), fp_nl(ACC[5])); \
  unsigned P3 = pkbf(fp_nl(ACC[6]), fp_nl(ACC[7])); \
  swap32(P0, P2); swap32(P1, P3); \
  PFST(KC, mk4(P0, P1, P2, P3)); \
} while (0)
#define REPACK_HI_L(ACC, KC) do { \
  unsigned P4 = pkbf(fp_nl(ACC[8]),  fp_nl(ACC[9])); \
  unsigned P5 = pkbf(fp_nl(ACC[10]), fp_nl(ACC[11])); \
  unsigned P6 = pkbf(fp_nl(ACC[12]), fp_nl(ACC[13])); \
  unsigned P7 = pkbf(fp_nl(ACC[14]), fp_nl(ACC[15])); \
  swap32(P4, P6); swap32(P5, P7); \
  PFST(KC, mk4(P4, P5, P6, P7)); \
} while (0)

#define FORR_LO(M_) M_(pfA0,0) M_(pfA1,16) M_(pfA2,32) M_(pfA3,48) M_(pfA4,64) M_(pfA5,80) \
                    M_(pfA6,96) M_(pfA7,112) M_(pfA8,128) M_(pfA9,144) M_(pfA10,160) M_(pfA11,176) M_(pfA12,192)
#define FORR_HI(M_) M_(pfA0,8) M_(pfA1,24) M_(pfA2,40) M_(pfA3,56) M_(pfA4,72) M_(pfA5,88) \
                    M_(pfA6,104) M_(pfA7,120) M_(pfA8,136) M_(pfA9,152) M_(pfA10,168) M_(pfA11,184)
#define FORL_LO(M_) M_(0,0) M_(1,16) M_(2,32) M_(3,48) M_(4,64) M_(5,80) \
                    M_(6,96) M_(7,112) M_(8,128) M_(9,144) M_(10,160) M_(11,176) M_(12,192)
#define FORL_HI(M_) M_(0,8) M_(1,24) M_(2,40) M_(3,56) M_(4,72) M_(5,88) \
                    M_(6,104) M_(7,120) M_(8,136) M_(9,152) M_(10,168) M_(11,184)

#define INX(PF, BB) PF = mk4( \
  pkbf(xcv[((BB) + 0) % 10], xcv[((BB) + 1) % 10]), \
  pkbf(xcv[((BB) + 2) % 10], xcv[((BB) + 3) % 10]), \
  pkbf(xcv[((BB) + 4) % 10], xcv[((BB) + 5) % 10]), \
  pkbf(xcv[((BB) + 6) % 10], xcv[((BB) + 7) % 10]));

#define E1W(W, F) { bins[(F) / 10] += bf2f((unsigned short)((W) & 0xFFFFu)); \
                    bins[((F) + 1) / 10] += bf2f((unsigned short)((W) >> 16)); }
#define E1PF(PF, BB) { E1W(PF[0], (BB) + 0) E1W(PF[1], (BB) + 2) E1W(PF[2], (BB) + 4) E1W(PF[3], (BB) + 6) }

#define E2AW(W, F) { ta[(F) % 10] += bf2f((unsigned short)((W) & 0xFFFFu)); \
                     ta[((F) + 1) % 10] += bf2f((unsigned short)((W) >> 16)); }
#define E2APF(KC, BB) { const uint4v W_ = PFLD(KC); \
  E2AW(W_[0], (BB) + 0) E2AW(W_[1], (BB) + 2) E2AW(W_[2], (BB) + 4) E2AW(W_[3], (BB) + 6) }

// 256 threads (4 waves, 1/SIMD): the only spill-free config (R1/R9/R10).
__global__ __launch_bounds__(256, 1) void tem_main(
    const float* __restrict__ xin, const float* __restrict__ gin,
    const float* __restrict__ Min, const float* __restrict__ Wc,
    const float* __restrict__ W1ie, const float* __restrict__ b1ie,
    const float* __restrict__ W2ie, const float* __restrict__ b2ie,
    const float* __restrict__ W1gg, const float* __restrict__ b1gg,
    const float* __restrict__ W2gg, const float* __restrict__ b2gg,
    const float* __restrict__ Wsp, const float* __restrict__ bsp,
    float* __restrict__ o_ginf, float* __restrict__ o_xinf,
    unsigned short* __restrict__ dWp, unsigned short* __restrict__ sWp) {
  // LDS: 96768 + 53248 + 2560 + 10240 = 162816 B
  __shared__ __attribute__((aligned(16))) unsigned short Ms[224 * MS_KS];
  __shared__ __attribute__((aligned(16))) unsigned Pb[4 * 13 * 64 * 4];
  __shared__ unsigned short xcS[128 * 10];
  __shared__ float g2S[128 * 20];

  const int tid = threadIdx.x;
  const int lane = tid & 63;
  const int wid = tid >> 6;      // 0..3
  const int cl = lane & 31;
  const int hi = lane >> 5;
  const int pbW = wid * 13;      // per-wave Pb fragment base

  {
    unsigned* Ms32 = (unsigned*)Ms;
    for (int i = tid; i < 224 * MS_KS / 2; i += 256) Ms32[i] = 0u;
  }
  __syncthreads();
  for (int i = tid; i < 200 * 224; i += 256) {
    const int k = i / 224, n = i - k * 224;
    if (n < 200) {
      float v = Min[k * 200 + n];
      if (k == n) v += KAPPA;
      Ms[n * MS_KS + k] = f2bf(v);
    }
  }

#pragma unroll 1
  for (int chunk = 0; chunk < 4; ++chunk) {
    const int r0 = (blockIdx.x * 4 + chunk) * 128;

    __syncthreads();   // Ms ready (chunk 0) / all waves done with Pb,xcS,g2S (chunks 1+)

    // prologue (streaming MLPs: compact code, same math)
    if (tid < 128) {
      const int rq = r0 + tid;
      float gv[20];
#pragma unroll
      for (int i = 0; i < 20; ++i) gv[i] = gin[(size_t)rq * 20 + i];
      float out20[20];
#pragma unroll
      for (int o = 0; o < 20; ++o) out20[o] = b2gg[o];
#pragma unroll 1
      for (int u = 0; u < 40; ++u) {
        float hu = b1gg[u];
#pragma unroll
        for (int i = 0; i < 20; ++i) hu += gv[i] * W1gg[i * 40 + u];
        hu = (hu > 0.f) ? hu : (expf(hu) - 1.f);
#pragma unroll
        for (int o = 0; o < 20; ++o) out20[o] += hu * W2gg[u * 20 + o];
      }
#pragma unroll
      for (int o = 0; o < 20; ++o) g2S[tid * 20 + o] = tanhf(out20[o]);
    } else {
      const int rr2 = tid - 128;
      const int rq = r0 + rr2;
      float xc[10];
#pragma unroll
      for (int o = 0; o < 10; ++o) xc[o] = 0.f;
#pragma unroll 1
      for (int j = 0; j < 45; ++j) {
        const float xv = xin[(size_t)rq * 45 + j];
#pragma unroll
        for (int o = 0; o < 10; ++o) xc[o] += xv * Wc[j * 10 + o];
      }
#pragma unroll
      for (int o = 0; o < 10; ++o) xcS[rr2 * 10 + o] = f2bf(xc[o]);
    }
    __syncthreads();

    const int rr = wid * 32 + cl;   // block-row this lane owns (0..127)
    const int r = r0 + rr;          // global row

    // ---- init ret0 (registers, unrolled - pfA must be named)
    uint4v pfA0, pfA1, pfA2, pfA3, pfA4, pfA5, pfA6, pfA7, pfA8, pfA9, pfA10, pfA11, pfA12;
    {
      float xcv[10];
#pragma unroll
      for (int o = 0; o < 10; ++o) xcv[o] = bf2f(xcS[rr * 10 + o]);
      if (hi == 0) { FORR_LO(INX) }
      else         { FORR_HI(INX) pfA12 = mk4(0u, 0u, 0u, 0u); }
    }
    // ---- init ret1 (LDS-resident, runtime loop reading g2S directly)
#pragma unroll 1
    for (int kc = 0; kc < 13; ++kc) {
      const int BB = kc * 16 + hi * 8;
      if (BB < 200) {
        unsigned w0 = pkbf(g2S[rr * 20 + (BB + 0) / 10], g2S[rr * 20 + (BB + 1) / 10]);
        unsigned w1 = pkbf(g2S[rr * 20 + (BB + 2) / 10], g2S[rr * 20 + (BB + 3) / 10]);
        unsigned w2 = pkbf(g2S[rr * 20 + (BB + 4) / 10], g2S[rr * 20 + (BB + 5) / 10]);
        unsigned w3 = pkbf(g2S[rr * 20 + (BB + 6) / 10], g2S[rr * 20 + (BB + 7) / 10]);
        PFST(kc, mk4(w0, w1, w2, w3));
      } else {
        PFST(kc, mk4(0u, 0u, 0u, 0u));
      }
    }

    // ---- 5 dual attractor iterations (barrier-free: wave-private Pb, RO Ms)
#pragma unroll 1
    for (int it = 0; it < 5; ++it) {
      f32x16 accA0 = {}, accA1 = {}, accA2 = {}, accA3 = {}, accA4 = {}, accA5 = {}, accA6 = {};
      f32x16 accB0 = {}, accB1 = {}, accB2 = {}, accB3 = {}, accB4 = {}, accB5 = {}, accB6 = {};
      STEP2(pfA0, 0);  STEP2(pfA1, 1);  STEP2(pfA2, 2);  STEP2(pfA3, 3);
      STEP2(pfA4, 4);  STEP2(pfA5, 5);  STEP2(pfA6, 6);  STEP2(pfA7, 7);
      STEP2(pfA8, 8);  STEP2(pfA9, 9);  STEP2(pfA10, 10); STEP2(pfA11, 11);
      STEP2(pfA12, 12);
      REPACK_LO_R(accA0, pfA0);  REPACK_HI_R(accA0, pfA1);
      REPACK_LO_R(accA1, pfA2);  REPACK_HI_R(accA1, pfA3);
      REPACK_LO_R(accA2, pfA4);  REPACK_HI_R(accA2, pfA5);
      REPACK_LO_R(accA3, pfA6);  REPACK_HI_R(accA3, pfA7);
      REPACK_LO_R(accA4, pfA8);  REPACK_HI_R(accA4, pfA9);
      REPACK_LO_R(accA5, pfA10); REPACK_HI_R(accA5, pfA11);
      REPACK_LO_R(accA6, pfA12);
      REPACK_LO_L(accB0, 0);  REPACK_HI_L(accB0, 1);
      REPACK_LO_L(accB1, 2);  REPACK_HI_L(accB1, 3);
      REPACK_LO_L(accB2, 4);  REPACK_HI_L(accB2, 5);
      REPACK_LO_L(accB3, 6);  REPACK_HI_L(accB3, 7);
      REPACK_LO_L(accB4, 8);  REPACK_HI_L(accB4, 9);
      REPACK_LO_L(accB5, 10); REPACK_HI_L(accB5, 11);
      REPACK_LO_L(accB6, 12);             // hi half of tile 6 (n=208..223) dropped
    }

    // ---- E1: g_inf from ret0 (streaming MLP; bins via unrolled frag scan)
    {
      float bins[20];
#pragma unroll
      for (int t = 0; t < 20; ++t) bins[t] = 0.f;
      if (hi == 0) { FORR_LO(E1PF) } else { FORR_HI(E1PF) }
#pragma unroll
      for (int t = 0; t < 20; ++t) bins[t] += __shfl_xor(bins[t], 32);
      float out20[20];
#pragma unroll
      for (int o = 0; o < 20; ++o) out20[o] = b2ie[o];
#pragma unroll 1
      for (int u = 0; u < 40; ++u) {
        float hu = b1ie[u];
#pragma unroll
        for (int gg = 0; gg < 20; ++gg) hu += bins[gg] * W1ie[gg * 40 + u];
        hu = (hu > 0.f) ? hu : (expf(hu) - 1.f);
#pragma unroll
        for (int o = 0; o < 20; ++o) out20[o] += hu * W2ie[u * 20 + o];
      }
#pragma unroll
      for (int oi = 0; oi < 10; ++oi) {
        const float v = hi ? out20[10 + oi] : out20[oi];
        o_ginf[(size_t)r * 20 + hi * 10 + oi] = fminf(1.f, fmaxf(-1.f, v));
      }
    }
    // ---- E2a: x_inf from ret1 (Pb fragments)
    {
      float ta[10];
#pragma unroll
      for (int t = 0; t < 10; ++t) ta[t] = 0.f;
      if (hi == 0) { FORL_LO(E2APF) } else { FORL_HI(E2APF) }
#pragma unroll
      for (int t = 0; t < 10; ++t) ta[t] += __shfl_xor(ta[t], 32);
      const int o0 = hi ? 23 : 0, o1 = hi ? 45 : 23;
#pragma unroll 1
      for (int o = o0; o < o1; ++o) {
        float v = bsp[o];
#pragma unroll
        for (int a = 0; a < 10; ++a) v += ta[a] * Wsp[a * 45 + o];
        o_xinf[(size_t)r * 45 + o] = v;
      }
    }
    // ---- E2b: d/s staging - row-major coalesced packed u32 (R9 path)
    __syncthreads();   // all waves' final ret1 REPACKs visible
    {
      unsigned int* dW32 = (unsigned int*)dWp;
      unsigned int* sW32 = (unsigned int*)sWp;
#pragma unroll 1
      for (int i = tid; i < 128 * 100; i += 256) {
        const int rD = i / 100, jp = i - rD * 100;
        const int j0 = jp * 2;
        const int wD = rD >> 5, clD = rD & 31;
        const int kcf = j0 >> 4, rem = j0 & 15;
        const int hif = rem >> 3, jw = (rem & 7) >> 1;
        const unsigned word = Pb[((wD * 13 + kcf) * 64 + hif * 32 + clD) * 4 + jw];
        const float p0 = bf2f((unsigned short)(word & 0xFFFFu));
        const float p1 = bf2f((unsigned short)(word >> 16));
        const float x0 = bf2f(xcS[rD * 10 + (j0 % 10)]);
        const float x1 = bf2f(xcS[rD * 10 + ((j0 + 1) % 10)]);
        const float pi0 = fp_nl(g2S[rD * 20 + (j0 / 10)] * x0);
        const float pi1 = fp_nl(g2S[rD * 20 + ((j0 + 1) / 10)] * x1);
        const unsigned dpack = (unsigned)f2bf(pi0 - p0) | ((unsigned)f2bf(pi1 - p1) << 16);
        const unsigned spack = (unsigned)f2bf(pi0 + p0) | ((unsigned)f2bf(pi1 + p1) << 16);
        const size_t idx = (size_t)(r0 + rD) * 100 + jp;
        dW32[idx] = dpack;
        sW32[idx] = spack;
      }
    }
  }
}

// hebb: row-major d/s input, LDS transpose, split-K. 256 blocks (full chip).
__global__ __launch_bounds__(448, 1) void tem_hebb(
    const unsigned short* __restrict__ dWp, const unsigned short* __restrict__ sWp,
    float* __restrict__ oM) {
  __shared__ __attribute__((aligned(16))) unsigned short dT[224 * HB_RS];
  __shared__ __attribute__((aligned(16))) unsigned short sT[224 * HB_RS];
  const int tid = threadIdx.x;
  const int lane = tid & 63, wid = tid >> 6;   // 7 waves
  const int cl = lane & 31, hi = lane >> 5;
  for (int i = tid; i < 224 * HB_RS; i += 448) { dT[i] = 0; sT[i] = 0; }
  f32x16 hacc[7];
#pragma unroll
  for (int nt = 0; nt < 7; ++nt)
#pragma unroll
    for (int q = 0; q < 16; ++q) hacc[nt][q] = 0.f;
  const int kbase = blockIdx.x * 512;
#pragma unroll 1
  for (int sub = 0; sub < 8; ++sub) {
    __syncthreads();
    const int kb = kbase + sub * 64;
#pragma unroll 1
    for (int i = tid; i < 64 * 50; i += 448) {
      const int rr = i / 50, fq = i - rr * 50;
      const int f0 = fq * 4;
      const short4v d4 = *(const short4v*)(dWp + ((size_t)(kb + rr) * 200 + f0));
      const short4v s4 = *(const short4v*)(sWp + ((size_t)(kb + rr) * 200 + f0));
#pragma unroll
      for (int q = 0; q < 4; ++q) {
        dT[(f0 + q) * HB_RS + rr] = (unsigned short)d4[q];
        sT[(f0 + q) * HB_RS + rr] = (unsigned short)s4[q];
      }
    }
    __syncthreads();
#pragma unroll
    for (int kc = 0; kc < 4; ++kc) {
      const short8 af = *(const short8*)(dT + ((wid * 32 + cl) * HB_RS + kc * 16 + hi * 8));
#pragma unroll
      for (int nt = 0; nt < 7; ++nt) {
        const short8 bfr = *(const short8*)(sT + ((nt * 32 + cl) * HB_RS + kc * 16 + hi * 8));
        hacc[nt] = __builtin_amdgcn_mfma_f32_32x32x16_bf16(af, bfr, hacc[nt], 0, 0, 0);
      }
    }
  }
  const float scale = YITA / (float)B_TOTAL;
#pragma unroll
  for (int nt = 0; nt < 7; ++nt) {
    const int j = nt * 32 + cl;
    if (j < 200) {
#pragma unroll
      for (int rg = 0; rg < 16; ++rg) {
        const int ii = wid * 32 + (rg & 3) + 8 * (rg >> 2) + 4 * hi;
        if (ii < 200) atomicAdd(&oM[ii * 200 + j], hacc[nt][rg] * scale);
      }
    }
  }
}

extern "C" void kernel_launch(void* const* d_in, const int* in_sizes, int n_in,
                              void* d_out, int out_size, void* d_ws, size_t ws_size,
                              hipStream_t stream) {
  (void)in_sizes; (void)n_in; (void)out_size; (void)ws_size;
  const float* xin  = (const float*)d_in[0];
  const float* gin  = (const float*)d_in[1];
  const float* Min  = (const float*)d_in[2];
  const float* Wc   = (const float*)d_in[3];
  const float* W1ie = (const float*)d_in[4];
  const float* b1ie = (const float*)d_in[5];
  const float* W2ie = (const float*)d_in[6];
  const float* b2ie = (const float*)d_in[7];
  const float* W1gg = (const float*)d_in[8];
  const float* b1gg = (const float*)d_in[9];
  const float* W2gg = (const float*)d_in[10];
  const float* b2gg = (const float*)d_in[11];
  const float* Wsp  = (const float*)d_in[12];
  const float* bsp  = (const float*)d_in[13];

  float* out = (float*)d_out;
  float* o_ginf = out;
  float* o_xinf = out + (size_t)B_TOTAL * 20;
  float* o_g    = out + (size_t)B_TOTAL * 65;
  float* o_x    = out + (size_t)B_TOTAL * 265;
  float* o_M    = out + (size_t)B_TOTAL * 465;

  unsigned short* dWp = (unsigned short*)d_ws;
  unsigned short* sWp = dWp + (size_t)B_TOTAL * PD;

  tem_init_m<<<(PD * PD + 255) / 256, 256, 0, stream>>>(Min, o_M);
  tem_pre<<<1024, 256, 0, stream>>>(xin, gin, Wc, W1gg, b1gg, W2gg, b2gg, o_g, o_x);
  tem_main<<<256, 256, 0, stream>>>(xin, gin, Min, Wc, W1ie, b1ie, W2ie, b2ie,
                                    W1gg, b1gg, W2gg, b2gg, Wsp, bsp,
                                    o_ginf, o_xinf, dWp, sWp);
  tem_hebb<<<256, 448, 0, stream>>>(dWp, sWp, o_M);
}

// Round 12
// 495.244 us; speedup vs baseline: 1.3650x; 1.3650x over previous
//
#include <hip/hip_runtime.h>

#define B_TOTAL 131072
#define PD 200
#define KAPPA 0.8f
#define LAMDA 0.9999f
#define YITA 0.5f
#define MS_KS 216   // M LDS k-stride (27 16B slots, odd -> minimal-conflict A reads)
#define HB_RS 72    // hebb LDS row-stride (9 slots, odd)

typedef short short8 __attribute__((ext_vector_type(8)));
typedef short short4v __attribute__((ext_vector_type(4)));
typedef float f32x16 __attribute__((ext_vector_type(16)));
typedef unsigned uint4v __attribute__((ext_vector_type(4)));

static __device__ __forceinline__ float bf2f(unsigned short h) {
  union { unsigned u; float f; } v; v.u = ((unsigned)h) << 16; return v.f;
}
static __device__ __forceinline__ unsigned short f2bf(float f) {
  union { float f; unsigned u; } v; v.f = f;
  unsigned r = v.u + 0x7FFFu + ((v.u >> 16) & 1u);
  return (unsigned short)(r >> 16);
}
static __device__ __forceinline__ float fp_nl(float v) {  // clip(leaky_relu(v),-1,1)
  float t = fmaxf(v, 0.01f * v);
  return fminf(1.f, fmaxf(-1.f, t));
}
static __device__ __forceinline__ unsigned pkbf(float lo, float hi) {
  unsigned r;
  asm("v_cvt_pk_bf16_f32 %0, %1, %2" : "=v"(r) : "v"(lo), "v"(hi));
  return r;
}
// verified R2-R11: swaps 32-lane halves between a,b
static __device__ __forceinline__ void swap32(unsigned &a, unsigned &b) {
  asm("s_nop 1\n\tv_permlane32_swap_b32 %0, %1" : "+v"(a), "+v"(b));
}
static __device__ __forceinline__ uint4v mk4(unsigned a, unsigned b, unsigned c, unsigned d) {
  uint4v v; v[0] = a; v[1] = b; v[2] = c; v[3] = d; return v;
}
static __device__ __forceinline__ short8 u4s8(uint4v w) {
  union { uint4v u; short8 s; } x; x.u = w; return x.s;
}

__global__ void tem_init_m(const float* __restrict__ Min, float* __restrict__ oM) {
  int i = blockIdx.x * 256 + threadIdx.x;
  if (i < PD * PD) oM[i] = LAMDA * Min[i];
}

// ---- tem_pre: high-occupancy kernel owning the o_g / o_x expansion (R11-proven).
__global__ __launch_bounds__(256, 4) void tem_pre(
    const float* __restrict__ xin, const float* __restrict__ gin,
    const float* __restrict__ Wc,
    const float* __restrict__ W1gg, const float* __restrict__ b1gg,
    const float* __restrict__ W2gg, const float* __restrict__ b2gg,
    float* __restrict__ o_g, float* __restrict__ o_x) {
  __shared__ unsigned short xcS[128 * 10];
  __shared__ float g2S[128 * 20];
  const int tid = threadIdx.x;
  const int r0 = blockIdx.x * 128;

  if (tid < 128) {
    const int rq = r0 + tid;
    float gv[20];
#pragma unroll
    for (int i = 0; i < 20; ++i) gv[i] = gin[(size_t)rq * 20 + i];
    float out20[20];
#pragma unroll
    for (int o = 0; o < 20; ++o) out20[o] = b2gg[o];
#pragma unroll 1
    for (int u = 0; u < 40; ++u) {
      float hu = b1gg[u];
#pragma unroll
      for (int i = 0; i < 20; ++i) hu += gv[i] * W1gg[i * 40 + u];
      hu = (hu > 0.f) ? hu : (expf(hu) - 1.f);
#pragma unroll
      for (int o = 0; o < 20; ++o) out20[o] += hu * W2gg[u * 20 + o];
    }
#pragma unroll
    for (int o = 0; o < 20; ++o) g2S[tid * 20 + o] = tanhf(out20[o]);
  } else {
    const int rr2 = tid - 128;
    const int rq = r0 + rr2;
    float xc[10];
#pragma unroll
    for (int o = 0; o < 10; ++o) xc[o] = 0.f;
#pragma unroll 1
    for (int j = 0; j < 45; ++j) {
      const float xv = xin[(size_t)rq * 45 + j];
#pragma unroll
      for (int o = 0; o < 10; ++o) xc[o] += xv * Wc[j * 10 + o];
    }
#pragma unroll
    for (int o = 0; o < 10; ++o) xcS[rr2 * 10 + o] = f2bf(xc[o]);
  }
  __syncthreads();
  for (int i = tid; i < 128 * 200; i += 256) {
    const int rP = i / 200, j = i - rP * 200;
    o_g[(size_t)(r0 + rP) * 200 + j] = g2S[rP * 20 + j / 10];
    o_x[(size_t)(r0 + rP) * 200 + j] = bf2f(xcS[rP * 10 + (j % 10)]);
  }
}

// ---- tem_main R12: 512 threads (8 waves = 2 waves/SIMD -> 2x latency hiding).
// Respect the 128-VGPR/wave cap at 8-wave blocks (R2-R4 lesson): acc in AGPRs
// (R7-proven "+a" asm, separate 128-AGPR budget), pf in 13 named VGPR quads
// (52 VGPR, R6-proven), retrievals SEQUENTIAL. No Pb. E2b goes through a
// 4KB/wave rotating LDS stage so global writes stay coalesced (R9 lesson).
#define LDMS(nt, kc) (*(const short8*)(Ms + (((nt) * 32 + cl) * MS_KS + (kc) * 16 + hi * 8)))
#define MFMA_AG(ACC, A, B) asm("v_mfma_f32_32x32x16_bf16 %0, %1, %2, %0" : "+a"(ACC) : "v"(A), "v"(B))

#define STEP(PF, KC) do { \
  const short8 _b = u4s8(PF); \
  { const short8 _a = LDMS(0, KC); MFMA_AG(acc0, _a, _b); } \
  { const short8 _a = LDMS(1, KC); MFMA_AG(acc1, _a, _b); } \
  { const short8 _a = LDMS(2, KC); MFMA_AG(acc2, _a, _b); } \
  { const short8 _a = LDMS(3, KC); MFMA_AG(acc3, _a, _b); } \
  { const short8 _a = LDMS(4, KC); MFMA_AG(acc4, _a, _b); } \
  { const short8 _a = LDMS(5, KC); MFMA_AG(acc5, _a, _b); } \
  { const short8 _a = LDMS(6, KC); MFMA_AG(acc6, _a, _b); } \
  __builtin_amdgcn_sched_barrier(0); \
} while (0)

#define REPACK_LO(ACC, PF) do { \
  unsigned P0 = pkbf(fp_nl(ACC[0]), fp_nl(ACC[1])); \
  unsigned P1 = pkbf(fp_nl(ACC[2]), fp_nl(ACC[3])); \
  unsigned P2 = pkbf(fp_nl(ACC[4]), fp_nl(ACC[5])); \
  unsigned P3 = pkbf(fp_nl(ACC[6]), fp_nl(ACC[7])); \
  swap32(P0, P2); swap32(P1, P3); \
  PF = mk4(P0, P1, P2, P3); \
} while (0)
#define REPACK_HI(ACC, PF) do { \
  unsigned P4 = pkbf(fp_nl(ACC[8]),  fp_nl(ACC[9])); \
  unsigned P5 = pkbf(fp_nl(ACC[10]), fp_nl(ACC[11])); \
  unsigned P6 = pkbf(fp_nl(ACC[12]), fp_nl(ACC[13])); \
  unsigned P7 = pkbf(fp_nl(ACC[14]), fp_nl(ACC[15])); \
  swap32(P4, P6); swap32(P5, P7); \
  PF = mk4(P4, P5, P6, P7); \
} while (0)

#define ITER5 do { \
  f32x16 acc0 = {}, acc1 = {}, acc2 = {}, acc3 = {}, acc4 = {}, acc5 = {}, acc6 = {}; \
  STEP(pfA0, 0);  STEP(pfA1, 1);  STEP(pfA2, 2);  STEP(pfA3, 3); \
  STEP(pfA4, 4);  STEP(pfA5, 5);  STEP(pfA6, 6);  STEP(pfA7, 7); \
  STEP(pfA8, 8);  STEP(pfA9, 9);  STEP(pfA10, 10); STEP(pfA11, 11); \
  STEP(pfA12, 12); \
  REPACK_LO(acc0, pfA0);  REPACK_HI(acc0, pfA1); \
  REPACK_LO(acc1, pfA2);  REPACK_HI(acc1, pfA3); \
  REPACK_LO(acc2, pfA4);  REPACK_HI(acc2, pfA5); \
  REPACK_LO(acc3, pfA6);  REPACK_HI(acc3, pfA7); \
  REPACK_LO(acc4, pfA8);  REPACK_HI(acc4, pfA9); \
  REPACK_LO(acc5, pfA10); REPACK_HI(acc5, pfA11); \
  REPACK_LO(acc6, pfA12); \
} while (0)

#define FORR_LO(M_) M_(pfA0,0) M_(pfA1,16) M_(pfA2,32) M_(pfA3,48) M_(pfA4,64) M_(pfA5,80) \
                    M_(pfA6,96) M_(pfA7,112) M_(pfA8,128) M_(pfA9,144) M_(pfA10,160) M_(pfA11,176) M_(pfA12,192)
#define FORR_HI(M_) M_(pfA0,8) M_(pfA1,24) M_(pfA2,40) M_(pfA3,56) M_(pfA4,72) M_(pfA5,88) \
                    M_(pfA6,104) M_(pfA7,120) M_(pfA8,136) M_(pfA9,152) M_(pfA10,168) M_(pfA11,184)

#define INX(PF, BB) PF = mk4( \
  pkbf(xcv[((BB) + 0) % 10], xcv[((BB) + 1) % 10]), \
  pkbf(xcv[((BB) + 2) % 10], xcv[((BB) + 3) % 10]), \
  pkbf(xcv[((BB) + 4) % 10], xcv[((BB) + 5) % 10]), \
  pkbf(xcv[((BB) + 6) % 10], xcv[((BB) + 7) % 10]));
#define ING(PF, BB) PF = mk4( \
  pkbf(g2v[((BB) + 0) / 10], g2v[((BB) + 1) / 10]), \
  pkbf(g2v[((BB) + 2) / 10], g2v[((BB) + 3) / 10]), \
  pkbf(g2v[((BB) + 4) / 10], g2v[((BB) + 5) / 10]), \
  pkbf(g2v[((BB) + 6) / 10], g2v[((BB) + 7) / 10]));

#define E1W(W, F) { bins[(F) / 10] += bf2f((unsigned short)((W) & 0xFFFFu)); \
                    bins[((F) + 1) / 10] += bf2f((unsigned short)((W) >> 16)); }
#define E1PF(PF, BB) { E1W(PF[0], (BB) + 0) E1W(PF[1], (BB) + 2) E1W(PF[2], (BB) + 4) E1W(PF[3], (BB) + 6) }

#define E2AW(W, F) { ta[(F) % 10] += bf2f((unsigned short)((W) & 0xFFFFu)); \
                     ta[((F) + 1) % 10] += bf2f((unsigned short)((W) >> 16)); }
#define E2APF(PF, BB) { E2AW(PF[0], (BB) + 0) E2AW(PF[1], (BB) + 2) E2AW(PF[2], (BB) + 4) E2AW(PF[3], (BB) + 6) }

// stage a pf quad into this wave's rotating LDS slot (chunk slot SL in 0..3)
#define STG(PF, SL) (((uint4v*)Stg)[(wid * 4 + (SL)) * 64 + lane] = PF)

__global__ __launch_bounds__(512, 1) void tem_main(
    const float* __restrict__ xin, const float* __restrict__ gin,
    const float* __restrict__ Min, const float* __restrict__ Wc,
    const float* __restrict__ W1ie, const float* __restrict__ b1ie,
    const float* __restrict__ W2ie, const float* __restrict__ b2ie,
    const float* __restrict__ W1gg, const float* __restrict__ b1gg,
    const float* __restrict__ W2gg, const float* __restrict__ b2gg,
    const float* __restrict__ Wsp, const float* __restrict__ bsp,
    float* __restrict__ o_ginf, float* __restrict__ o_xinf,
    unsigned short* __restrict__ dWp, unsigned short* __restrict__ sWp) {
  // LDS: 96768 + 5120 + 20480 + 32768 = 155136 B
  __shared__ __attribute__((aligned(16))) unsigned short Ms[224 * MS_KS];
  __shared__ unsigned short xcS[256 * 10];
  __shared__ float g2S[256 * 20];
  __shared__ __attribute__((aligned(16))) unsigned Stg[8 * 4 * 64 * 4];

  const int tid = threadIdx.x;
  const int lane = tid & 63;
  const int wid = tid >> 6;      // 0..7
  const int cl = lane & 31;
  const int hi = lane >> 5;
  const int r0 = blockIdx.x * 256;

  {
    unsigned* Ms32 = (unsigned*)Ms;
    for (int i = tid; i < 224 * MS_KS / 2; i += 512) Ms32[i] = 0u;
  }
  __syncthreads();
  for (int i = tid; i < 200 * 224; i += 512) {
    const int k = i / 224, n = i - k * 224;
    if (n < 200) {
      float v = Min[k * 200 + n];
      if (k == n) v += KAPPA;
      Ms[n * MS_KS + k] = f2bf(v);
    }
  }

  // prologue (R10 unrolled form - R11 streaming regressed): t<256 g2, t>=256 xc
  if (tid < 256) {
    const int rq = r0 + tid;
    float gv[20];
#pragma unroll
    for (int i = 0; i < 20; ++i) gv[i] = gin[(size_t)rq * 20 + i];
    float h[40];
#pragma unroll
    for (int u = 0; u < 40; ++u) h[u] = b1gg[u];
#pragma unroll
    for (int i = 0; i < 20; ++i)
#pragma unroll
      for (int u = 0; u < 40; ++u) h[u] += gv[i] * W1gg[i * 40 + u];
#pragma unroll
    for (int u = 0; u < 40; ++u) h[u] = (h[u] > 0.f) ? h[u] : (expf(h[u]) - 1.f);
#pragma unroll
    for (int o = 0; o < 20; ++o) {
      float v = b2gg[o];
#pragma unroll
      for (int u = 0; u < 40; ++u) v += h[u] * W2gg[u * 20 + o];
      g2S[tid * 20 + o] = tanhf(v);
    }
  } else {
    const int rr2 = tid - 256;
    const int rq = r0 + rr2;
    float xc[10];
#pragma unroll
    for (int o = 0; o < 10; ++o) xc[o] = 0.f;
#pragma unroll 1
    for (int j = 0; j < 45; ++j) {
      const float xv = xin[(size_t)rq * 45 + j];
#pragma unroll
      for (int o = 0; o < 10; ++o) xc[o] += xv * Wc[j * 10 + o];
    }
#pragma unroll
    for (int o = 0; o < 10; ++o) xcS[rr2 * 10 + o] = f2bf(xc[o]);
  }
  __syncthreads();

  const int rr = wid * 32 + cl;   // block-row this lane owns (0..255)
  const int r = r0 + rr;          // global row

  uint4v pfA0, pfA1, pfA2, pfA3, pfA4, pfA5, pfA6, pfA7, pfA8, pfA9, pfA10, pfA11, pfA12;

  // ================= ret0: x-cue =================
  {
    float xcv[10];
#pragma unroll
    for (int o = 0; o < 10; ++o) xcv[o] = bf2f(xcS[rr * 10 + o]);
    if (hi == 0) { FORR_LO(INX) }
    else         { FORR_HI(INX) pfA12 = mk4(0u, 0u, 0u, 0u); }
  }
#pragma unroll 1
  for (int it = 0; it < 5; ++it) { ITER5; }
  // E1: g_inf (unrolled MLP)
  {
    float bins[20];
#pragma unroll
    for (int t = 0; t < 20; ++t) bins[t] = 0.f;
    if (hi == 0) { FORR_LO(E1PF) } else { FORR_HI(E1PF) }
#pragma unroll
    for (int t = 0; t < 20; ++t) bins[t] += __shfl_xor(bins[t], 32);
    float h[40];
#pragma unroll
    for (int u = 0; u < 40; ++u) h[u] = b1ie[u];
#pragma unroll
    for (int gg = 0; gg < 20; ++gg) {
      const float bv = bins[gg];
#pragma unroll
      for (int u = 0; u < 40; ++u) h[u] += bv * W1ie[gg * 40 + u];
    }
#pragma unroll
    for (int u = 0; u < 40; ++u) h[u] = (h[u] > 0.f) ? h[u] : (expf(h[u]) - 1.f);
#pragma unroll
    for (int oi = 0; oi < 10; ++oi) {
      const int o = hi * 10 + oi;
      float v = b2ie[o];
#pragma unroll
      for (int u = 0; u < 40; ++u) v += h[u] * W2ie[u * 20 + o];
      o_ginf[(size_t)r * 20 + o] = fminf(1.f, fmaxf(-1.f, v));
    }
  }

  // ================= ret1: g-cue =================
  {
    float g2v[20];
#pragma unroll
    for (int o = 0; o < 20; ++o) g2v[o] = g2S[rr * 20 + o];
    if (hi == 0) { FORR_LO(ING) }
    else         { FORR_HI(ING) pfA12 = mk4(0u, 0u, 0u, 0u); }
  }
#pragma unroll 1
  for (int it = 0; it < 5; ++it) { ITER5; }
  // E2a: x_inf
  {
    float ta[10];
#pragma unroll
    for (int t = 0; t < 10; ++t) ta[t] = 0.f;
    if (hi == 0) { FORR_LO(E2APF) } else { FORR_HI(E2APF) }
#pragma unroll
    for (int t = 0; t < 10; ++t) ta[t] += __shfl_xor(ta[t], 32);
    const int o0 = hi ? 23 : 0, o1 = hi ? 45 : 23;
#pragma unroll 1
    for (int o = o0; o < o1; ++o) {
      float v = bsp[o];
#pragma unroll
      for (int a = 0; a < 10; ++a) v += ta[a] * Wsp[a * 45 + o];
      o_xinf[(size_t)r * 45 + o] = v;
    }
  }
  // E2b: d/s staging via 4KB/wave rotating LDS (wave-private, coalesced out)
  {
    unsigned int* dW32 = (unsigned int*)dWp;
    unsigned int* sW32 = (unsigned int*)sWp;
#pragma unroll 1
    for (int rnd = 0; rnd < 4; ++rnd) {
      // stage this round's chunks (literal dispatch, wave-private slots)
      if (rnd == 0)      { STG(pfA0, 0);  STG(pfA1, 1);  STG(pfA2, 2);   STG(pfA3, 3);  }
      else if (rnd == 1) { STG(pfA4, 0);  STG(pfA5, 1);  STG(pfA6, 2);   STG(pfA7, 3);  }
      else if (rnd == 2) { STG(pfA8, 0);  STG(pfA9, 1);  STG(pfA10, 2);  STG(pfA11, 3); }
      else               { STG(pfA12, 0); }
      asm volatile("s_waitcnt lgkmcnt(0)" ::: "memory");   // wave-sync LDS visibility
      __builtin_amdgcn_sched_barrier(0);                    // rule #18 fence
      const int nIt = (rnd == 3) ? 2 : 16;   // rnd3: chunk 12 lo-half only (jp 96..99)
#pragma unroll 1
      for (int itw = 0; itw < nIt; ++itw) {
        const int idx = itw * 64 + lane;
        const int row = idx >> 5;            // 0..31 within wave
        const int jpo = idx & 31;            // jp offset within round
        const int jp = rnd * 32 + jpo;
        if (jp < 100) {
          const int kcl = jpo >> 3, rem = jpo & 7;
          const int hi2 = rem >> 2, jw = rem & 3;
          const unsigned word = Stg[(((wid * 4 + kcl) * 2 + hi2) * 32 + row) * 4 + jw];
          const int rB = wid * 32 + row;     // block-row
          const int j0 = jp * 2;
          const float p0 = bf2f((unsigned short)(word & 0xFFFFu));
          const float p1 = bf2f((unsigned short)(word >> 16));
          const float x0 = bf2f(xcS[rB * 10 + (j0 % 10)]);
          const float x1 = bf2f(xcS[rB * 10 + ((j0 + 1) % 10)]);
          const float pi0 = fp_nl(g2S[rB * 20 + (j0 / 10)] * x0);
          const float pi1 = fp_nl(g2S[rB * 20 + ((j0 + 1) / 10)] * x1);
          const unsigned dpack = (unsigned)f2bf(pi0 - p0) | ((unsigned)f2bf(pi1 - p1) << 16);
          const unsigned spack = (unsigned)f2bf(pi0 + p0) | ((unsigned)f2bf(pi1 + p1) << 16);
          const size_t oidx = (size_t)(r0 + rB) * 100 + jp;
          dW32[oidx] = dpack;
          sW32[oidx] = spack;
        }
      }
      __builtin_amdgcn_sched_barrier(0);
    }
  }
}

// hebb: row-major d/s input, LDS transpose, split-K, 256 blocks (R11-proven).
__global__ __launch_bounds__(448, 1) void tem_hebb(
    const unsigned short* __restrict__ dWp, const unsigned short* __restrict__ sWp,
    float* __restrict__ oM) {
  __shared__ __attribute__((aligned(16))) unsigned short dT[224 * HB_RS];
  __shared__ __attribute__((aligned(16))) unsigned short sT[224 * HB_RS];
  const int tid = threadIdx.x;
  const int lane = tid & 63, wid = tid >> 6;   // 7 waves
  const int cl = lane & 31, hi = lane >> 5;
  for (int i = tid; i < 224 * HB_RS; i += 448) { dT[i] = 0; sT[i] = 0; }
  f32x16 hacc[7];
#pragma unroll
  for (int nt = 0; nt < 7; ++nt)
#pragma unroll
    for (int q = 0; q < 16; ++q) hacc[nt][q] = 0.f;
  const int kbase = blockIdx.x * 512;
#pragma unroll 1
  for (int sub = 0; sub < 8; ++sub) {
    __syncthreads();
    const int kb = kbase + sub * 64;
#pragma unroll 1
    for (int i = tid; i < 64 * 50; i += 448) {
      const int rr = i / 50, fq = i - rr * 50;
      const int f0 = fq * 4;
      const short4v d4 = *(const short4v*)(dWp + ((size_t)(kb + rr) * 200 + f0));
      const short4v s4 = *(const short4v*)(sWp + ((size_t)(kb + rr) * 200 + f0));
#pragma unroll
      for (int q = 0; q < 4; ++q) {
        dT[(f0 + q) * HB_RS + rr] = (unsigned short)d4[q];
        sT[(f0 + q) * HB_RS + rr] = (unsigned short)s4[q];
      }
    }
    __syncthreads();
#pragma unroll
    for (int kc = 0; kc < 4; ++kc) {
      const short8 af = *(const short8*)(dT + ((wid * 32 + cl) * HB_RS + kc * 16 + hi * 8));
#pragma unroll
      for (int nt = 0; nt < 7; ++nt) {
        const short8 bfr = *(const short8*)(sT + ((nt * 32 + cl) * HB_RS + kc * 16 + hi * 8));
        hacc[nt] = __builtin_amdgcn_mfma_f32_32x32x16_bf16(af, bfr, hacc[nt], 0, 0, 0);
      }
    }
  }
  const float scale = YITA / (float)B_TOTAL;
#pragma unroll
  for (int nt = 0; nt < 7; ++nt) {
    const int j = nt * 32 + cl;
    if (j < 200) {
#pragma unroll
      for (int rg = 0; rg < 16; ++rg) {
        const int ii = wid * 32 + (rg & 3) + 8 * (rg >> 2) + 4 * hi;
        if (ii < 200) atomicAdd(&oM[ii * 200 + j], hacc[nt][rg] * scale);
      }
    }
  }
}

extern "C" void kernel_launch(void* const* d_in, const int* in_sizes, int n_in,
                              void* d_out, int out_size, void* d_ws, size_t ws_size,
                              hipStream_t stream) {
  (void)in_sizes; (void)n_in; (void)out_size; (void)ws_size;
  const float* xin  = (const float*)d_in[0];
  const float* gin  = (const float*)d_in[1];
  const float* Min  = (const float*)d_in[2];
  const float* Wc   = (const float*)d_in[3];
  const float* W1ie = (const float*)d_in[4];
  const float* b1ie = (const float*)d_in[5];
  const float* W2ie = (const float*)d_in[6];
  const float* b2ie = (const float*)d_in[7];
  const float* W1gg = (const float*)d_in[8];
  const float* b1gg = (const float*)d_in[9];
  const float* W2gg = (const float*)d_in[10];
  const float* b2gg = (const float*)d_in[11];
  const float* Wsp  = (const float*)d_in[12];
  const float* bsp  = (const float*)d_in[13];

  float* out = (float*)d_out;
  float* o_ginf = out;
  float* o_xinf = out + (size_t)B_TOTAL * 20;
  float* o_g    = out + (size_t)B_TOTAL * 65;
  float* o_x    = out + (size_t)B_TOTAL * 265;
  float* o_M    = out + (size_t)B_TOTAL * 465;

  unsigned short* dWp = (unsigned short*)d_ws;
  unsigned short* sWp = dWp + (size_t)B_TOTAL * PD;

  tem_init_m<<<(PD * PD + 255) / 256, 256, 0, stream>>>(Min, o_M);
  tem_pre<<<1024, 256, 0, stream>>>(xin, gin, Wc, W1gg, b1gg, W2gg, b2gg, o_g, o_x);
  tem_main<<<512, 512, 0, stream>>>(xin, gin, Min, Wc, W1ie, b1ie, W2ie, b2ie,
                                    W1gg, b1gg, W2gg, b2gg, Wsp, bsp,
                                    o_ginf, o_xinf, dWp, sWp);
  tem_hebb<<<256, 448, 0, stream>>>(dWp, sWp, o_M);
}